// Round 9
// baseline (411.659 us; speedup 1.0000x reference)
//
#include <hip/hip_runtime.h>
#include <hip/hip_bf16.h>

#define T_SEQ   4096
#define B_BATCH 4
#define E_DIM   1024
#define D_HEAD  128
#define BT      (B_BATCH * T_SEQ)
#define CHUNK   512
#define KVB     32

using bf16x8 = __attribute__((ext_vector_type(8))) short;
using f32x4  = __attribute__((ext_vector_type(4))) float;

static __device__ __forceinline__ unsigned short f2bf(float f) {
    unsigned int b = __float_as_uint(f);
    return (unsigned short)((b + 0x7FFFu + ((b >> 16) & 1u)) >> 16);   // RNE
}
static __device__ __forceinline__ float bf2f(unsigned short u) {
    return __uint_as_float(((unsigned int)u) << 16);
}
// hi = truncated-bf16(x) (exact prefix), lo = bf16(x - hi); hi+lo ~ x to 2^-17
static __device__ __forceinline__ void split2(float f, unsigned short &h, unsigned short &l) {
    unsigned int b = __float_as_uint(f);
    h = (unsigned short)(b >> 16);
    l = f2bf(f - __uint_as_float(b & 0xFFFF0000u));
}
static __device__ __forceinline__ void split8(const float4 &a, const float4 &b,
                                              uint4 &hi, uint4 &lo) {
    float fa[8] = {a.x, a.y, a.z, a.w, b.x, b.y, b.z, b.w};
    unsigned int h[4], l[4];
    #pragma unroll
    for (int i = 0; i < 4; ++i) {
        unsigned short h0, h1, l0, l1;
        split2(fa[2 * i],     h0, l0);
        split2(fa[2 * i + 1], h1, l1);
        h[i] = (unsigned int)h0 | ((unsigned int)h1 << 16);
        l[i] = (unsigned int)l0 | ((unsigned int)l1 << 16);
    }
    hi = make_uint4(h[0], h[1], h[2], h[3]);
    lo = make_uint4(l[0], l[1], l[2], l[3]);
}

// ---------------------------------------------------------------------------
// Kernel 0: W -> Wt[zi][n=128][k=1024] bf16 hi/lo. grid (16,4,3), block 256.
// ---------------------------------------------------------------------------
__global__ __launch_bounds__(256) void prep_w_kernel(
    const float* __restrict__ Wq, const float* __restrict__ Wk,
    const float* __restrict__ Wv,
    unsigned short* __restrict__ wth, unsigned short* __restrict__ wtl)
{
    const int zi = blockIdx.z;
    const float* __restrict__ W = (zi == 0) ? Wq : (zi == 1) ? Wk : Wv;
    const int k0 = blockIdx.x * 64;
    const int n0 = blockIdx.y * 32;
    const int t  = threadIdx.x;
    __shared__ float S[64][36];

    #pragma unroll
    for (int i = 0; i < 2; ++i) {
        int f = t + i * 256;
        int r = f >> 3, c4 = f & 7;
        *(float4*)&S[r][c4 * 4] = *(const float4*)&W[(size_t)(k0 + r) * D_HEAD + n0 + c4 * 4];
    }
    __syncthreads();

    int n = t >> 3, kc = t & 7;
    unsigned int h[4], l[4];
    #pragma unroll
    for (int i = 0; i < 4; ++i) {
        unsigned short h0, h1, l0, l1;
        split2(S[kc * 8 + 2 * i][n],     h0, l0);
        split2(S[kc * 8 + 2 * i + 1][n], h1, l1);
        h[i] = (unsigned int)h0 | ((unsigned int)h1 << 16);
        l[i] = (unsigned int)l0 | ((unsigned int)l1 << 16);
    }
    size_t ofs = ((size_t)zi * 128 + n0 + n) * 1024 + k0 + kc * 8;
    *(uint4*)&wth[ofs] = make_uint4(h[0], h[1], h[2], h[3]);
    *(uint4*)&wtl[ofs] = make_uint4(l[0], l[1], l[2], l[3]);
}

// ---------------------------------------------------------------------------
// Kernel 1: QKV projection bf16 MFMA GEMM (3-pass hi/lo) + fused RoPE.
// ---------------------------------------------------------------------------
__global__ __launch_bounds__(256) void qkv_gemm_kernel(
    const float* __restrict__ x,
    const unsigned short* __restrict__ wth, const unsigned short* __restrict__ wtl,
    const float* __restrict__ fcos, const float* __restrict__ fsin,
    unsigned short* __restrict__ qh, unsigned short* __restrict__ qlo,
    unsigned short* __restrict__ kh, unsigned short* __restrict__ klo,
    unsigned short* __restrict__ vb)
{
    const int zi   = blockIdx.y;
    const int row0 = blockIdx.x * 64;
    const unsigned short* __restrict__ Bhg = wth + (size_t)zi * 128 * 1024;
    const unsigned short* __restrict__ Blg = wtl + (size_t)zi * 128 * 1024;

    __shared__ unsigned short Ah[64 * 32], Al[64 * 32];
    __shared__ unsigned short Bh[128 * 32], Bl[128 * 32];

    const int tid  = threadIdx.x;
    const int lane = tid & 63;
    const int w    = tid >> 6;
    const int wr   = w >> 1, wc = w & 1;
    const int colq = lane & 15;
    const int g    = lane >> 4;

    f32x4 acc[2][4];
    #pragma unroll
    for (int m = 0; m < 2; ++m)
        #pragma unroll
        for (int n = 0; n < 4; ++n) acc[m][n] = (f32x4){0.f, 0.f, 0.f, 0.f};

    const int ra = tid >> 2, ca = tid & 3;
    const int sa = ca ^ ((ra >> 1) & 3);
    char* AhB = (char*)Ah; char* AlB = (char*)Al;
    char* BhB = (char*)Bh; char* BlB = (char*)Bl;

    for (int k0 = 0; k0 < E_DIM; k0 += 32) {
        {
            const float* xp = &x[(size_t)(row0 + ra) * E_DIM + k0 + ca * 8];
            float4 a0 = *(const float4*)xp;
            float4 a1 = *(const float4*)(xp + 4);
            uint4 hi, lo;
            split8(a0, a1, hi, lo);
            *(uint4*)(AhB + ra * 64 + sa * 16) = hi;
            *(uint4*)(AlB + ra * 64 + sa * 16) = lo;
        }
        #pragma unroll
        for (int i = 0; i < 2; ++i) {
            int j  = tid + i * 256;
            int rb = j >> 2, cb = j & 3;
            int sb = cb ^ ((rb >> 1) & 3);
            size_t gofs = (size_t)rb * 1024 + k0 + cb * 8;
            *(uint4*)(BhB + rb * 64 + sb * 16) = *(const uint4*)&Bhg[gofs];
            *(uint4*)(BlB + rb * 64 + sb * 16) = *(const uint4*)&Blg[gofs];
        }
        __syncthreads();

        bf16x8 afh[2], afl[2], bfh[4], bfl[4];
        #pragma unroll
        for (int m = 0; m < 2; ++m) {
            int rowA = wr * 32 + m * 16 + colq;
            int off  = rowA * 64 + (g ^ ((rowA >> 1) & 3)) * 16;
            afh[m] = *(const bf16x8*)(AhB + off);
            afl[m] = *(const bf16x8*)(AlB + off);
        }
        #pragma unroll
        for (int n = 0; n < 4; ++n) {
            int rowB = wc * 64 + n * 16 + colq;
            int off  = rowB * 64 + (g ^ ((rowB >> 1) & 3)) * 16;
            bfh[n] = *(const bf16x8*)(BhB + off);
            bfl[n] = *(const bf16x8*)(BlB + off);
        }
        #pragma unroll
        for (int m = 0; m < 2; ++m)
            #pragma unroll
            for (int n = 0; n < 4; ++n) {
                acc[m][n] = __builtin_amdgcn_mfma_f32_16x16x32_bf16(afh[m], bfh[n], acc[m][n], 0, 0, 0);
                acc[m][n] = __builtin_amdgcn_mfma_f32_16x16x32_bf16(afl[m], bfh[n], acc[m][n], 0, 0, 0);
                acc[m][n] = __builtin_amdgcn_mfma_f32_16x16x32_bf16(afh[m], bfl[n], acc[m][n], 0, 0, 0);
            }
        __syncthreads();
    }

    const float SCALE = 0.08838834764831845f;
    #pragma unroll
    for (int m = 0; m < 2; ++m)
        #pragma unroll
        for (int n = 0; n < 4; ++n) {
            int col = wc * 64 + n * 16 + colq;
            int h   = col >> 1;
            #pragma unroll
            for (int r = 0; r < 4; ++r) {
                int row = row0 + wr * 32 + m * 16 + g * 4 + r;
                int t   = row & (T_SEQ - 1);
                float val = acc[m][n][r];
                size_t ofs = (size_t)row * D_HEAD + col;
                if (zi == 2) {
                    vb[ofs] = f2bf(val);
                } else {
                    float partner = __shfl_xor(val, 1, 64);
                    float c = fcos[t * 64 + h];
                    float s = fsin[t * 64 + h];
                    float o = (col & 1) ? (partner * s + val * c)
                                        : (val * c - partner * s);
                    if (zi == 0) o *= SCALE;
                    unsigned short hv, lv;
                    split2(o, hv, lv);
                    if (zi == 0) { qh[ofs] = hv; qlo[ofs] = lv; }
                    else         { kh[ofs] = hv; klo[ofs] = lv; }
                }
            }
        }
}

// ---------------------------------------------------------------------------
// Kernel 2: V transpose  vb[BT,128] -> vt[B][128][T]  (bf16)
// ---------------------------------------------------------------------------
__global__ __launch_bounds__(256) void vtrans_kernel(
    const unsigned short* __restrict__ vb,
    unsigned short* __restrict__ vt)
{
    const int t0 = (blockIdx.x & 63) * 64;
    const int b  = blockIdx.x >> 6;
    const int tid = threadIdx.x;
    __shared__ unsigned short S[64][132];

    #pragma unroll
    for (int i = 0; i < 8; ++i) {
        int idx = tid + i * 256;
        int t  = idx >> 5;
        int c4 = idx & 31;
        *reinterpret_cast<ushort4*>(&S[t][c4 * 4]) =
            *reinterpret_cast<const ushort4*>(&vb[(size_t)(b * T_SEQ + t0 + t) * 128 + c4 * 4]);
    }
    __syncthreads();
    #pragma unroll
    for (int i = 0; i < 8; ++i) {
        int idx = tid + i * 256;
        int d = idx >> 4;
        int c = idx & 15;
        ushort4 val;
        val.x = S[c * 4 + 0][d];
        val.y = S[c * 4 + 1][d];
        val.z = S[c * 4 + 2][d];
        val.w = S[c * 4 + 3][d];
        *reinterpret_cast<ushort4*>(&vt[((size_t)(b * 128 + d)) * T_SEQ + t0 + c * 4]) = val;
    }
}

// ---------------------------------------------------------------------------
// Kernel 3: MFMA flash-attention chunk:
//  - 256 threads = 4 waves, 128 queries/block (each wave 32 q as 2x16)
//  - reg-staged double-buffer: prefetch tile t+1 during tile t compute (T14)
//  - defer-max softmax (T13, THR=8): skip O-rescale when max doesn't grow
//  - causal mask only on diagonal-crossing subtiles (uniform branch)
// grid: 4*32*8 = 1024 (b, qt of 128 q, chunk of 512 keys)
// ---------------------------------------------------------------------------
__global__ __launch_bounds__(256) void attn_chunk_kernel(
    const unsigned short* __restrict__ qh, const unsigned short* __restrict__ qlo,
    const unsigned short* __restrict__ kh, const unsigned short* __restrict__ klo,
    const unsigned short* __restrict__ vt,   // [B][128][T]
    float* __restrict__ opart,               // [1024][128][128]
    float* __restrict__ mlpart)              // [1024][2][128]
{
    const int bid = blockIdx.x;
    const int c   = bid & 7;
    const int qt  = (bid >> 3) & 31;
    const int b   = bid >> 8;
    const int kstart = c * CHUNK;
    const int qend   = qt * 128 + 128;
    if (kstart >= qend) return;
    const int kend   = min(kstart + CHUNK, qend);
    const int ntiles = (kend - kstart) >> 5;

    const int tid  = threadIdx.x;
    const int w    = tid >> 6;
    const int lane = tid & 63;
    const int col  = lane & 15;
    const int g    = lane >> 4;
    const int qbw  = qt * 128 + w * 32;

    __shared__ unsigned short Kh[KVB * 128];       // 8 KB, XOR-swizzled rows
    __shared__ unsigned short Kl[KVB * 128];       // 8 KB
    __shared__ unsigned short Vts[128 * 40];       // 10 KB, 80B rows
    __shared__ unsigned short Pl[4][1024];         // per-wave P (32q x 32k)

    char* KhB = reinterpret_cast<char*>(Kh);
    char* KlB = reinterpret_cast<char*>(Kl);
    char* VtB = reinterpret_cast<char*>(Vts);
    char* PlB = reinterpret_cast<char*>(Pl[w]);

    // staging job coordinates: 2 K-jobs + 2 V-jobs per thread (256 thr)
    int kkey[2], kc16[2], klofs[2], vd[2], vcc[2], vlofs[2];
    #pragma unroll
    for (int i = 0; i < 2; ++i) {
        int j = tid + i * 256;
        kkey[i]  = j >> 4;  kc16[i] = j & 15;
        klofs[i] = (kkey[i] * 256 + kc16[i] * 16) ^ ((kkey[i] & 7) << 4);
        vd[i]    = j >> 2;  vcc[i]  = j & 3;
        vlofs[i] = vd[i] * 80 + vcc[i] * 16;
    }
    uint4 pkh[2], pkl[2], pv[2];
    auto fetch = [&](int kbase) {
        #pragma unroll
        for (int i = 0; i < 2; ++i) {
            size_t gk = ((size_t)(b * T_SEQ + kbase + kkey[i])) * 128 + kc16[i] * 8;
            pkh[i] = *reinterpret_cast<const uint4*>(&kh [gk]);
            pkl[i] = *reinterpret_cast<const uint4*>(&klo[gk]);
            size_t gv = ((size_t)(b * 128 + vd[i])) * T_SEQ + kbase + vcc[i] * 8;
            pv[i]  = *reinterpret_cast<const uint4*>(&vt[gv]);
        }
    };

    // ---- Q fragments (hoisted, hi/lo) ----
    bf16x8 qhf[2][4], qlf[2][4];
    #pragma unroll
    for (int s = 0; s < 2; ++s) {
        size_t qrow = (size_t)(b * T_SEQ + qbw + s * 16 + col);
        #pragma unroll
        for (int dc = 0; dc < 4; ++dc) {
            int off = dc * 32 + g * 8;
            qhf[s][dc] = *reinterpret_cast<const bf16x8*>(&qh [qrow * 128 + off]);
            qlf[s][dc] = *reinterpret_cast<const bf16x8*>(&qlo[qrow * 128 + off]);
        }
    }

    f32x4 oacc[2][8];
    #pragma unroll
    for (int s = 0; s < 2; ++s)
        #pragma unroll
        for (int db = 0; db < 8; ++db)
            oacc[s][db] = (f32x4){0.f, 0.f, 0.f, 0.f};
    float m_s[2] = {-3.0e38f, -3.0e38f};
    float l_s[2] = {0.f, 0.f};

    fetch(kstart);   // prologue prefetch

    for (int t = 0; t < ntiles; ++t) {
        const int kbase = kstart + t * KVB;

        __syncthreads();   // all waves done reading previous tile's LDS
        #pragma unroll
        for (int i = 0; i < 2; ++i) {
            *reinterpret_cast<uint4*>(KhB + klofs[i]) = pkh[i];
            *reinterpret_cast<uint4*>(KlB + klofs[i]) = pkl[i];
            *reinterpret_cast<uint4*>(VtB + vlofs[i]) = pv[i];
        }
        __syncthreads();
        if (t + 1 < ntiles) fetch(kbase + KVB);   // in flight during compute

        // ---- S^T = K . Q^T  (hi*hi + lo*hi + hi*lo) ----
        f32x4 st[2][2];
        st[0][0] = (f32x4){0,0,0,0}; st[0][1] = (f32x4){0,0,0,0};
        st[1][0] = (f32x4){0,0,0,0}; st[1][1] = (f32x4){0,0,0,0};
        #pragma unroll
        for (int kb = 0; kb < 2; ++kb) {
            #pragma unroll
            for (int dc = 0; dc < 4; ++dc) {
                int lofs = ((kb * 16 + col) * 256 + dc * 64 + g * 16) ^ ((col & 7) << 4);
                bf16x8 khf = *reinterpret_cast<const bf16x8*>(KhB + lofs);
                bf16x8 klf = *reinterpret_cast<const bf16x8*>(KlB + lofs);
                #pragma unroll
                for (int s = 0; s < 2; ++s) {
                    st[s][kb] = __builtin_amdgcn_mfma_f32_16x16x32_bf16(khf, qhf[s][dc], st[s][kb], 0, 0, 0);
                    st[s][kb] = __builtin_amdgcn_mfma_f32_16x16x32_bf16(klf, qhf[s][dc], st[s][kb], 0, 0, 0);
                    st[s][kb] = __builtin_amdgcn_mfma_f32_16x16x32_bf16(khf, qlf[s][dc], st[s][kb], 0, 0, 0);
                }
            }
        }

        // ---- mask (diagonal subtiles only) + defer-max online softmax ----
        #pragma unroll
        for (int s = 0; s < 2; ++s) {
            const int qg = qbw + s * 16 + col;
            if (kbase + KVB - 1 > qbw + s * 16) {          // wave-uniform
                #pragma unroll
                for (int kb = 0; kb < 2; ++kb) {
                    if (kbase + kb * 16 + 15 > qbw + s * 16) {
                        int keyb = kbase + kb * 16 + g * 4;
                        #pragma unroll
                        for (int r = 0; r < 4; ++r)
                            if (keyb + r > qg) st[s][kb][r] = -3.0e38f;
                    }
                }
            }
            float tmax = st[s][0][0];
            #pragma unroll
            for (int kb = 0; kb < 2; ++kb)
                #pragma unroll
                for (int r = 0; r < 4; ++r) tmax = fmaxf(tmax, st[s][kb][r]);
            tmax = fmaxf(tmax, __shfl_xor(tmax, 16, 64));
            tmax = fmaxf(tmax, __shfl_xor(tmax, 32, 64));

            if (!__all(tmax <= m_s[s] + 8.0f)) {           // rescale rarely
                float mnew = fmaxf(m_s[s], tmax);
                float corr = __expf(m_s[s] - mnew);
                m_s[s] = mnew;
                l_s[s] *= corr;
                #pragma unroll
                for (int r = 0; r < 4; ++r) {
                    float cr = __shfl(corr, (lane & 48) + g * 4 + r, 64);
                    #pragma unroll
                    for (int db = 0; db < 8; ++db) oacc[s][db][r] *= cr;
                }
            }
            float psum = 0.f;
            #pragma unroll
            for (int kb = 0; kb < 2; ++kb)
                #pragma unroll
                for (int r = 0; r < 4; ++r) {
                    float e = __expf(st[s][kb][r] - m_s[s]);
                    st[s][kb][r] = e;
                    psum += e;
                }
            psum += __shfl_xor(psum, 16, 64);
            psum += __shfl_xor(psum, 32, 64);
            l_s[s] += psum;

            // P -> LDS (bf16), swizzled
            int q = s * 16 + col;
            #pragma unroll
            for (int kb = 0; kb < 2; ++kb) {
                unsigned int pk0 = (unsigned int)f2bf(st[s][kb][0]) | ((unsigned int)f2bf(st[s][kb][1]) << 16);
                unsigned int pk1 = (unsigned int)f2bf(st[s][kb][2]) | ((unsigned int)f2bf(st[s][kb][3]) << 16);
                int base = q * 64 + (kb * 16 + g * 4) * 2;
                int sw = (q & 3) << 4;
                *reinterpret_cast<unsigned int*>(PlB + ((base    ) ^ sw)) = pk0;
                *reinterpret_cast<unsigned int*>(PlB + ((base + 4) ^ sw)) = pk1;
            }
        }

        // ---- O += P . V ----
        #pragma unroll
        for (int db = 0; db < 8; ++db) {
            int d = db * 16 + col;
            bf16x8 vf = *reinterpret_cast<const bf16x8*>(VtB + d * 80 + g * 16);
            #pragma unroll
            for (int s = 0; s < 2; ++s) {
                int lofs = ((s * 16 + col) * 64 + g * 16) ^ ((col & 3) << 4);
                bf16x8 pf = *reinterpret_cast<const bf16x8*>(PlB + lofs);
                oacc[s][db] = __builtin_amdgcn_mfma_f32_16x16x32_bf16(pf, vf, oacc[s][db], 0, 0, 0);
            }
        }
    }

    // ---- store partials ----
    const int pb = (b * 32 + qt) * 8 + c;
    float* op = opart + (size_t)pb * (128 * 128);
    #pragma unroll
    for (int s = 0; s < 2; ++s)
        #pragma unroll
        for (int db = 0; db < 8; ++db)
            #pragma unroll
            for (int r = 0; r < 4; ++r) {
                int qloc = w * 32 + s * 16 + g * 4 + r;
                op[qloc * 128 + db * 16 + col] = oacc[s][db][r];
            }
    if (g == 0) {
        float* ml = mlpart + (size_t)pb * 256;
        #pragma unroll
        for (int s = 0; s < 2; ++s) {
            ml[      w * 32 + s * 16 + col] = m_s[s];
            ml[128 + w * 32 + s * 16 + col] = l_s[s];
        }
    }
}

// ---------------------------------------------------------------------------
// Kernel 4: combine partials (128-q tiles, 8 chunks). grid: 4*32, block 256
// ---------------------------------------------------------------------------
__global__ __launch_bounds__(256) void combine_kernel(
    const float* __restrict__ opart, const float* __restrict__ mlpart,
    float* __restrict__ out)
{
    const int qt  = blockIdx.x & 31;
    const int b   = blockIdx.x >> 5;
    const int nch = ((qt * 128 + 127) >> 9) + 1;
    const int tid = threadIdx.x;
    const int q   = tid >> 1;          // 0..127
    const int d0  = (tid & 1) * 64;
    const int pb0 = (b * 32 + qt) * 8;

    float mv[8], wv[8];
    float M = -3.0e38f;
    #pragma unroll
    for (int cc = 0; cc < 8; ++cc)
        if (cc < nch) {
            mv[cc] = mlpart[(size_t)(pb0 + cc) * 256 + q];
            M = fmaxf(M, mv[cc]);
        }
    float L = 0.f;
    #pragma unroll
    for (int cc = 0; cc < 8; ++cc)
        if (cc < nch) {
            float wgt = __expf(mv[cc] - M);
            wv[cc] = wgt;
            L += mlpart[(size_t)(pb0 + cc) * 256 + 128 + q] * wgt;
        }
    float invL = 1.f / L;

    float4 acc[16];
    #pragma unroll
    for (int i = 0; i < 16; ++i) acc[i] = make_float4(0.f, 0.f, 0.f, 0.f);
    #pragma unroll
    for (int cc = 0; cc < 8; ++cc)
        if (cc < nch) {
            const float4* src = reinterpret_cast<const float4*>(
                &opart[((size_t)(pb0 + cc) * 128 + q) * 128 + d0]);
            float wgt = wv[cc] * invL;
            #pragma unroll
            for (int i = 0; i < 16; ++i) {
                float4 v = src[i];
                acc[i].x += wgt * v.x; acc[i].y += wgt * v.y;
                acc[i].z += wgt * v.z; acc[i].w += wgt * v.w;
            }
        }
    float4* dst = reinterpret_cast<float4*>(&out[((size_t)(b * T_SEQ + qt * 128 + q)) * 128 + d0]);
    #pragma unroll
    for (int i = 0; i < 16; ++i) dst[i] = acc[i];
}

// ---------------------------------------------------------------------------
extern "C" void kernel_launch(void* const* d_in, const int* in_sizes, int n_in,
                              void* d_out, int out_size, void* d_ws, size_t ws_size,
                              hipStream_t stream)
{
    (void)in_sizes; (void)n_in; (void)out_size; (void)ws_size;
    const float* x  = (const float*)d_in[0];
    const float* Wq = (const float*)d_in[1];
    const float* Wk = (const float*)d_in[2];
    const float* Wv = (const float*)d_in[3];
    const float* fc = (const float*)d_in[4];
    const float* fs = (const float*)d_in[5];
    float* out = (float*)d_out;

    const size_t NW = (size_t)3 * 128 * 1024;
    const size_t NE = (size_t)BT * 128;
    unsigned short* wth = (unsigned short*)d_ws;
    unsigned short* wtl = wth + NW;
    unsigned short* qh  = wtl + NW;
    unsigned short* qlo = qh  + NE;
    unsigned short* kh  = qlo + NE;
    unsigned short* klo = kh  + NE;
    unsigned short* vb  = klo + NE;
    unsigned short* vt  = vb  + NE;
    float* opart  = (float*)(vt + NE);                 // 1024*128*128 f32
    float* mlpart = opart + (size_t)1024 * 128 * 128;  // 1024*256 f32

    prep_w_kernel<<<dim3(16, 4, 3), 256, 0, stream>>>(Wq, Wk, Wv, wth, wtl);
    qkv_gemm_kernel<<<dim3(BT / 64, 3), 256, 0, stream>>>(
        x, wth, wtl, fc, fs, qh, qlo, kh, klo, vb);
    vtrans_kernel<<<256, 256, 0, stream>>>(vb, vt);
    attn_chunk_kernel<<<1024, 256, 0, stream>>>(qh, qlo, kh, klo, vt, opart, mlpart);
    combine_kernel<<<128, 256, 0, stream>>>(opart, mlpart, out);
}

// Round 12
// 315.236 us; speedup vs baseline: 1.3059x; 1.3059x over previous
//
#include <hip/hip_runtime.h>
#include <hip/hip_bf16.h>

#define T_SEQ   4096
#define B_BATCH 4
#define E_DIM   1024
#define D_HEAD  128
#define BT      (B_BATCH * T_SEQ)
#define CHUNK   256
#define KVB     32
#define NSLOT   544    // per-batch compact (qt, chunk) slots: sum_{qt<64}(qt/4+1)

using bf16x8 = __attribute__((ext_vector_type(8))) short;
using f32x4  = __attribute__((ext_vector_type(4))) float;

static __device__ __forceinline__ unsigned short f2bf(float f) {
    unsigned int b = __float_as_uint(f);
    return (unsigned short)((b + 0x7FFFu + ((b >> 16) & 1u)) >> 16);   // RNE
}
static __device__ __forceinline__ float bf2f(unsigned short u) {
    return __uint_as_float(((unsigned int)u) << 16);
}
// hi = truncated-bf16(x) (exact prefix), lo = bf16(x - hi); hi+lo ~ x to 2^-17
static __device__ __forceinline__ void split2(float f, unsigned short &h, unsigned short &l) {
    unsigned int b = __float_as_uint(f);
    h = (unsigned short)(b >> 16);
    l = f2bf(f - __uint_as_float(b & 0xFFFF0000u));
}
static __device__ __forceinline__ void split8(const float4 &a, const float4 &b,
                                              uint4 &hi, uint4 &lo) {
    float fa[8] = {a.x, a.y, a.z, a.w, b.x, b.y, b.z, b.w};
    unsigned int h[4], l[4];
    #pragma unroll
    for (int i = 0; i < 4; ++i) {
        unsigned short h0, h1, l0, l1;
        split2(fa[2 * i],     h0, l0);
        split2(fa[2 * i + 1], h1, l1);
        h[i] = (unsigned int)h0 | ((unsigned int)h1 << 16);
        l[i] = (unsigned int)l0 | ((unsigned int)l1 << 16);
    }
    hi = make_uint4(h[0], h[1], h[2], h[3]);
    lo = make_uint4(l[0], l[1], l[2], l[3]);
}
// compact slot prefix: cum(qt) = sum_{j<qt} (j/4 + 1)
static __device__ __forceinline__ int cumslot(int qt) {
    int m = qt >> 2, r = qt & 3;
    return 2 * m * (m - 1) + r * m + qt;
}

// ---------------------------------------------------------------------------
// Kernel 0: W -> Wt[zi][n=128][k=1024] bf16 hi/lo. grid (16,4,3), block 256.
// ---------------------------------------------------------------------------
__global__ __launch_bounds__(256) void prep_w_kernel(
    const float* __restrict__ Wq, const float* __restrict__ Wk,
    const float* __restrict__ Wv,
    unsigned short* __restrict__ wth, unsigned short* __restrict__ wtl)
{
    const int zi = blockIdx.z;
    const float* __restrict__ W = (zi == 0) ? Wq : (zi == 1) ? Wk : Wv;
    const int k0 = blockIdx.x * 64;
    const int n0 = blockIdx.y * 32;
    const int t  = threadIdx.x;
    __shared__ float S[64][36];

    #pragma unroll
    for (int i = 0; i < 2; ++i) {
        int f = t + i * 256;
        int r = f >> 3, c4 = f & 7;
        *(float4*)&S[r][c4 * 4] = *(const float4*)&W[(size_t)(k0 + r) * D_HEAD + n0 + c4 * 4];
    }
    __syncthreads();

    int n = t >> 3, kc = t & 7;
    unsigned int h[4], l[4];
    #pragma unroll
    for (int i = 0; i < 4; ++i) {
        unsigned short h0, h1, l0, l1;
        split2(S[kc * 8 + 2 * i][n],     h0, l0);
        split2(S[kc * 8 + 2 * i + 1][n], h1, l1);
        h[i] = (unsigned int)h0 | ((unsigned int)h1 << 16);
        l[i] = (unsigned int)l0 | ((unsigned int)l1 << 16);
    }
    size_t ofs = ((size_t)zi * 128 + n0 + n) * 1024 + k0 + kc * 8;
    *(uint4*)&wth[ofs] = make_uint4(h[0], h[1], h[2], h[3]);
    *(uint4*)&wtl[ofs] = make_uint4(l[0], l[1], l[2], l[3]);
}

// ---------------------------------------------------------------------------
// Kernel 1: QKV projection bf16 MFMA GEMM (3-pass hi/lo) + fused RoPE.
// ---------------------------------------------------------------------------
__global__ __launch_bounds__(256) void qkv_gemm_kernel(
    const float* __restrict__ x,
    const unsigned short* __restrict__ wth, const unsigned short* __restrict__ wtl,
    const float* __restrict__ fcos, const float* __restrict__ fsin,
    unsigned short* __restrict__ qh, unsigned short* __restrict__ qlo,
    unsigned short* __restrict__ kh, unsigned short* __restrict__ klo,
    unsigned short* __restrict__ vb)
{
    const int zi   = blockIdx.y;
    const int row0 = blockIdx.x * 64;
    const unsigned short* __restrict__ Bhg = wth + (size_t)zi * 128 * 1024;
    const unsigned short* __restrict__ Blg = wtl + (size_t)zi * 128 * 1024;

    __shared__ unsigned short Ah[64 * 32], Al[64 * 32];
    __shared__ unsigned short Bh[128 * 32], Bl[128 * 32];

    const int tid  = threadIdx.x;
    const int lane = tid & 63;
    const int w    = tid >> 6;
    const int wr   = w >> 1, wc = w & 1;
    const int colq = lane & 15;
    const int g    = lane >> 4;

    f32x4 acc[2][4];
    #pragma unroll
    for (int m = 0; m < 2; ++m)
        #pragma unroll
        for (int n = 0; n < 4; ++n) acc[m][n] = (f32x4){0.f, 0.f, 0.f, 0.f};

    const int ra = tid >> 2, ca = tid & 3;
    const int sa = ca ^ ((ra >> 1) & 3);
    char* AhB = (char*)Ah; char* AlB = (char*)Al;
    char* BhB = (char*)Bh; char* BlB = (char*)Bl;

    for (int k0 = 0; k0 < E_DIM; k0 += 32) {
        {
            const float* xp = &x[(size_t)(row0 + ra) * E_DIM + k0 + ca * 8];
            float4 a0 = *(const float4*)xp;
            float4 a1 = *(const float4*)(xp + 4);
            uint4 hi, lo;
            split8(a0, a1, hi, lo);
            *(uint4*)(AhB + ra * 64 + sa * 16) = hi;
            *(uint4*)(AlB + ra * 64 + sa * 16) = lo;
        }
        #pragma unroll
        for (int i = 0; i < 2; ++i) {
            int j  = tid + i * 256;
            int rb = j >> 2, cb = j & 3;
            int sb = cb ^ ((rb >> 1) & 3);
            size_t gofs = (size_t)rb * 1024 + k0 + cb * 8;
            *(uint4*)(BhB + rb * 64 + sb * 16) = *(const uint4*)&Bhg[gofs];
            *(uint4*)(BlB + rb * 64 + sb * 16) = *(const uint4*)&Blg[gofs];
        }
        __syncthreads();

        bf16x8 afh[2], afl[2], bfh[4], bfl[4];
        #pragma unroll
        for (int m = 0; m < 2; ++m) {
            int rowA = wr * 32 + m * 16 + colq;
            int off  = rowA * 64 + (g ^ ((rowA >> 1) & 3)) * 16;
            afh[m] = *(const bf16x8*)(AhB + off);
            afl[m] = *(const bf16x8*)(AlB + off);
        }
        #pragma unroll
        for (int n = 0; n < 4; ++n) {
            int rowB = wc * 64 + n * 16 + colq;
            int off  = rowB * 64 + (g ^ ((rowB >> 1) & 3)) * 16;
            bfh[n] = *(const bf16x8*)(BhB + off);
            bfl[n] = *(const bf16x8*)(BlB + off);
        }
        #pragma unroll
        for (int m = 0; m < 2; ++m)
            #pragma unroll
            for (int n = 0; n < 4; ++n) {
                acc[m][n] = __builtin_amdgcn_mfma_f32_16x16x32_bf16(afh[m], bfh[n], acc[m][n], 0, 0, 0);
                acc[m][n] = __builtin_amdgcn_mfma_f32_16x16x32_bf16(afl[m], bfh[n], acc[m][n], 0, 0, 0);
                acc[m][n] = __builtin_amdgcn_mfma_f32_16x16x32_bf16(afh[m], bfl[n], acc[m][n], 0, 0, 0);
            }
        __syncthreads();
    }

    const float SCALE = 0.08838834764831845f;
    #pragma unroll
    for (int m = 0; m < 2; ++m)
        #pragma unroll
        for (int n = 0; n < 4; ++n) {
            int col = wc * 64 + n * 16 + colq;
            int h   = col >> 1;
            #pragma unroll
            for (int r = 0; r < 4; ++r) {
                int row = row0 + wr * 32 + m * 16 + g * 4 + r;
                int t   = row & (T_SEQ - 1);
                float val = acc[m][n][r];
                size_t ofs = (size_t)row * D_HEAD + col;
                if (zi == 2) {
                    vb[ofs] = f2bf(val);
                } else {
                    float partner = __shfl_xor(val, 1, 64);
                    float c = fcos[t * 64 + h];
                    float s = fsin[t * 64 + h];
                    float o = (col & 1) ? (partner * s + val * c)
                                        : (val * c - partner * s);
                    if (zi == 0) o *= SCALE;
                    unsigned short hv, lv;
                    split2(o, hv, lv);
                    if (zi == 0) { qh[ofs] = hv; qlo[ofs] = lv; }
                    else         { kh[ofs] = hv; klo[ofs] = lv; }
                }
            }
        }
}

// ---------------------------------------------------------------------------
// Kernel 2: V transpose  vb[BT,128] -> vt[B][128][T]  (bf16)
// ---------------------------------------------------------------------------
__global__ __launch_bounds__(256) void vtrans_kernel(
    const unsigned short* __restrict__ vb,
    unsigned short* __restrict__ vt)
{
    const int t0 = (blockIdx.x & 63) * 64;
    const int b  = blockIdx.x >> 6;
    const int tid = threadIdx.x;
    __shared__ unsigned short S[64][132];

    #pragma unroll
    for (int i = 0; i < 8; ++i) {
        int idx = tid + i * 256;
        int t  = idx >> 5;
        int c4 = idx & 31;
        *reinterpret_cast<ushort4*>(&S[t][c4 * 4]) =
            *reinterpret_cast<const ushort4*>(&vb[(size_t)(b * T_SEQ + t0 + t) * 128 + c4 * 4]);
    }
    __syncthreads();
    #pragma unroll
    for (int i = 0; i < 8; ++i) {
        int idx = tid + i * 256;
        int d = idx >> 4;
        int c = idx & 15;
        ushort4 val;
        val.x = S[c * 4 + 0][d];
        val.y = S[c * 4 + 1][d];
        val.z = S[c * 4 + 2][d];
        val.w = S[c * 4 + 3][d];
        *reinterpret_cast<ushort4*>(&vt[((size_t)(b * 128 + d)) * T_SEQ + t0 + c * 4]) = val;
    }
}

// ---------------------------------------------------------------------------
// Kernel 3: MFMA flash-attention chunk — round-5 structure + validated tweaks:
//  - 128 threads = 2 waves, 64 queries/block (wave w: 32 q as 2x16)
//  - CHUNK=256 -> 2176 active blocks, <=8 k-tiles each (balanced tail)
//  - LPT dispatch: heaviest q-tiles first (qt = 63 - bid_qt)
//  - defer-max softmax (T13, THR=8) + diagonal-only causal mask (validated r9)
//  - direct LDS staging (no reg-prefetch; saves 32 VGPR)
// grid: 4*64*16 = 4096 (b, qt of 64 q, chunk of 256 keys); inactive return.
// ---------------------------------------------------------------------------
__global__ __launch_bounds__(128, 4) void attn_chunk_kernel(
    const unsigned short* __restrict__ qh, const unsigned short* __restrict__ qlo,
    const unsigned short* __restrict__ kh, const unsigned short* __restrict__ klo,
    const unsigned short* __restrict__ vt,   // [B][128][T]
    float* __restrict__ opart,               // [4*NSLOT][64][128]
    float* __restrict__ mlpart)              // [4*NSLOT][2][64]
{
    const int bid = blockIdx.x;
    const int c   = bid & 15;
    const int qt  = 63 - ((bid >> 4) & 63);   // LPT: heavy tiles dispatch first
    const int b   = bid >> 10;
    const int kstart = c * CHUNK;
    const int qend   = qt * 64 + 64;
    if (kstart >= qend) return;
    const int kend   = min(kstart + CHUNK, qend);
    const int ntiles = (kend - kstart) >> 5;

    const int tid  = threadIdx.x;
    const int w    = tid >> 6;
    const int lane = tid & 63;
    const int col  = lane & 15;
    const int g    = lane >> 4;
    const int qbw  = qt * 64 + w * 32;

    __shared__ unsigned short Kh[KVB * 128];       // 8 KB, XOR-swizzled rows
    __shared__ unsigned short Kl[KVB * 128];       // 8 KB
    __shared__ unsigned short Vts[128 * 40];       // 10 KB, 80B rows
    __shared__ unsigned short Pl[2][1024];         // per-wave P (32q x 32k)

    char* KhB = reinterpret_cast<char*>(Kh);
    char* KlB = reinterpret_cast<char*>(Kl);
    char* VtB = reinterpret_cast<char*>(Vts);
    char* PlB = reinterpret_cast<char*>(Pl[w]);

    // ---- Q fragments (hoisted, hi/lo) ----
    bf16x8 qhf[2][4], qlf[2][4];
    #pragma unroll
    for (int s = 0; s < 2; ++s) {
        size_t qrow = (size_t)(b * T_SEQ + qbw + s * 16 + col);
        #pragma unroll
        for (int dc = 0; dc < 4; ++dc) {
            int off = dc * 32 + g * 8;
            qhf[s][dc] = *reinterpret_cast<const bf16x8*>(&qh [qrow * 128 + off]);
            qlf[s][dc] = *reinterpret_cast<const bf16x8*>(&qlo[qrow * 128 + off]);
        }
    }

    f32x4 oacc[2][8];
    #pragma unroll
    for (int s = 0; s < 2; ++s)
        #pragma unroll
        for (int db = 0; db < 8; ++db)
            oacc[s][db] = (f32x4){0.f, 0.f, 0.f, 0.f};
    float m_s[2] = {-3.0e38f, -3.0e38f};
    float l_s[2] = {0.f, 0.f};

    for (int t = 0; t < ntiles; ++t) {
        const int kbase = kstart + t * KVB;

        // ---- stage K hi/lo (32x128, XOR-swizzled) + V^T (128x32, 80B rows) ----
        #pragma unroll
        for (int i = 0; i < 4; ++i) {
            int idx = tid + i * 128;
            int key = idx >> 4, c16 = idx & 15;
            size_t gofs = ((size_t)(b * T_SEQ + kbase + key)) * 128 + c16 * 8;
            int lofs = (key * 256 + c16 * 16) ^ ((key & 7) << 4);
            *reinterpret_cast<uint4*>(KhB + lofs) = *reinterpret_cast<const uint4*>(&kh [gofs]);
            *reinterpret_cast<uint4*>(KlB + lofs) = *reinterpret_cast<const uint4*>(&klo[gofs]);
        }
        #pragma unroll
        for (int i = 0; i < 4; ++i) {
            int idx = tid + i * 128;
            int d = idx >> 2, c16 = idx & 3;
            size_t gofs = ((size_t)(b * 128 + d)) * T_SEQ + kbase + c16 * 8;
            int lofs = d * 80 + c16 * 16;
            *reinterpret_cast<uint4*>(VtB + lofs) = *reinterpret_cast<const uint4*>(&vt[gofs]);
        }
        __syncthreads();

        // ---- S^T = K . Q^T  (hi*hi + lo*hi + hi*lo) ----
        f32x4 st[2][2];
        st[0][0] = (f32x4){0,0,0,0}; st[0][1] = (f32x4){0,0,0,0};
        st[1][0] = (f32x4){0,0,0,0}; st[1][1] = (f32x4){0,0,0,0};
        #pragma unroll
        for (int kb = 0; kb < 2; ++kb) {
            #pragma unroll
            for (int dc = 0; dc < 4; ++dc) {
                int lofs = ((kb * 16 + col) * 256 + dc * 64 + g * 16) ^ ((col & 7) << 4);
                bf16x8 khf = *reinterpret_cast<const bf16x8*>(KhB + lofs);
                bf16x8 klf = *reinterpret_cast<const bf16x8*>(KlB + lofs);
                #pragma unroll
                for (int s = 0; s < 2; ++s) {
                    st[s][kb] = __builtin_amdgcn_mfma_f32_16x16x32_bf16(khf, qhf[s][dc], st[s][kb], 0, 0, 0);
                    st[s][kb] = __builtin_amdgcn_mfma_f32_16x16x32_bf16(klf, qhf[s][dc], st[s][kb], 0, 0, 0);
                    st[s][kb] = __builtin_amdgcn_mfma_f32_16x16x32_bf16(khf, qlf[s][dc], st[s][kb], 0, 0, 0);
                }
            }
        }

        // ---- mask (diagonal subtiles only) + defer-max online softmax ----
        #pragma unroll
        for (int s = 0; s < 2; ++s) {
            const int qg = qbw + s * 16 + col;
            if (kbase + KVB - 1 > qbw + s * 16) {          // wave-uniform
                #pragma unroll
                for (int kb = 0; kb < 2; ++kb) {
                    if (kbase + kb * 16 + 15 > qbw + s * 16) {
                        int keyb = kbase + kb * 16 + g * 4;
                        #pragma unroll
                        for (int r = 0; r < 4; ++r)
                            if (keyb + r > qg) st[s][kb][r] = -3.0e38f;
                    }
                }
            }
            float tmax = st[s][0][0];
            #pragma unroll
            for (int kb = 0; kb < 2; ++kb)
                #pragma unroll
                for (int r = 0; r < 4; ++r) tmax = fmaxf(tmax, st[s][kb][r]);
            tmax = fmaxf(tmax, __shfl_xor(tmax, 16, 64));
            tmax = fmaxf(tmax, __shfl_xor(tmax, 32, 64));

            if (!__all(tmax <= m_s[s] + 8.0f)) {           // rescale rarely
                float mnew = fmaxf(m_s[s], tmax);
                float corr = __expf(m_s[s] - mnew);
                m_s[s] = mnew;
                l_s[s] *= corr;
                #pragma unroll
                for (int r = 0; r < 4; ++r) {
                    float cr = __shfl(corr, (lane & 48) + g * 4 + r, 64);
                    #pragma unroll
                    for (int db = 0; db < 8; ++db) oacc[s][db][r] *= cr;
                }
            }
            float psum = 0.f;
            #pragma unroll
            for (int kb = 0; kb < 2; ++kb)
                #pragma unroll
                for (int r = 0; r < 4; ++r) {
                    float e = __expf(st[s][kb][r] - m_s[s]);
                    st[s][kb][r] = e;
                    psum += e;
                }
            psum += __shfl_xor(psum, 16, 64);
            psum += __shfl_xor(psum, 32, 64);
            l_s[s] += psum;

            // P -> LDS (bf16), swizzled
            int q = s * 16 + col;
            #pragma unroll
            for (int kb = 0; kb < 2; ++kb) {
                unsigned int pk0 = (unsigned int)f2bf(st[s][kb][0]) | ((unsigned int)f2bf(st[s][kb][1]) << 16);
                unsigned int pk1 = (unsigned int)f2bf(st[s][kb][2]) | ((unsigned int)f2bf(st[s][kb][3]) << 16);
                int base = q * 64 + (kb * 16 + g * 4) * 2;
                int sw = (q & 3) << 4;
                *reinterpret_cast<unsigned int*>(PlB + ((base    ) ^ sw)) = pk0;
                *reinterpret_cast<unsigned int*>(PlB + ((base + 4) ^ sw)) = pk1;
            }
        }

        // ---- O += P . V ----
        #pragma unroll
        for (int db = 0; db < 8; ++db) {
            int d = db * 16 + col;
            bf16x8 vf = *reinterpret_cast<const bf16x8*>(VtB + d * 80 + g * 16);
            #pragma unroll
            for (int s = 0; s < 2; ++s) {
                int lofs = ((s * 16 + col) * 64 + g * 16) ^ ((col & 3) << 4);
                bf16x8 pf = *reinterpret_cast<const bf16x8*>(PlB + lofs);
                oacc[s][db] = __builtin_amdgcn_mfma_f32_16x16x32_bf16(pf, vf, oacc[s][db], 0, 0, 0);
            }
        }
        __syncthreads();   // before next tile overwrites LDS
    }

    // ---- store partials (compact slot) ----
    const int pb = b * NSLOT + cumslot(qt) + c;
    float* op = opart + (size_t)pb * (64 * 128);
    #pragma unroll
    for (int s = 0; s < 2; ++s)
        #pragma unroll
        for (int db = 0; db < 8; ++db)
            #pragma unroll
            for (int r = 0; r < 4; ++r) {
                int qloc = w * 32 + s * 16 + g * 4 + r;
                op[qloc * 128 + db * 16 + col] = oacc[s][db][r];
            }
    if (g == 0) {
        float* ml = mlpart + (size_t)pb * 128;
        #pragma unroll
        for (int s = 0; s < 2; ++s) {
            ml[     w * 32 + s * 16 + col] = m_s[s];
            ml[64 + w * 32 + s * 16 + col] = l_s[s];
        }
    }
}

// ---------------------------------------------------------------------------
// Kernel 4: combine partials (64-q tiles, up to 16 chunks). grid 4*64, blk 256
// ---------------------------------------------------------------------------
__global__ __launch_bounds__(256) void combine_kernel(
    const float* __restrict__ opart, const float* __restrict__ mlpart,
    float* __restrict__ out)
{
    const int qt  = blockIdx.x & 63;
    const int b   = blockIdx.x >> 6;
    const int nch = (qt >> 2) + 1;
    const int tid = threadIdx.x;
    const int q   = tid >> 2;          // 0..63
    const int d0  = (tid & 3) * 32;
    const int pb0 = b * NSLOT + cumslot(qt);

    float mv[16], wv[16];
    float M = -3.0e38f;
    #pragma unroll
    for (int cc = 0; cc < 16; ++cc)
        if (cc < nch) {
            mv[cc] = mlpart[(size_t)(pb0 + cc) * 128 + q];
            M = fmaxf(M, mv[cc]);
        }
    float L = 0.f;
    #pragma unroll
    for (int cc = 0; cc < 16; ++cc)
        if (cc < nch) {
            float wgt = __expf(mv[cc] - M);
            wv[cc] = wgt;
            L += mlpart[(size_t)(pb0 + cc) * 128 + 64 + q] * wgt;
        }
    float invL = 1.f / L;

    float4 acc[8];
    #pragma unroll
    for (int i = 0; i < 8; ++i) acc[i] = make_float4(0.f, 0.f, 0.f, 0.f);
    #pragma unroll
    for (int cc = 0; cc < 16; ++cc)
        if (cc < nch) {
            const float4* src = reinterpret_cast<const float4*>(
                &opart[((size_t)(pb0 + cc) * 64 + q) * 128 + d0]);
            float wgt = wv[cc] * invL;
            #pragma unroll
            for (int i = 0; i < 8; ++i) {
                float4 v = src[i];
                acc[i].x += wgt * v.x; acc[i].y += wgt * v.y;
                acc[i].z += wgt * v.z; acc[i].w += wgt * v.w;
            }
        }
    float4* dst = reinterpret_cast<float4*>(&out[((size_t)(b * T_SEQ + qt * 64 + q)) * 128 + d0]);
    #pragma unroll
    for (int i = 0; i < 8; ++i) dst[i] = acc[i];
}

// ---------------------------------------------------------------------------
extern "C" void kernel_launch(void* const* d_in, const int* in_sizes, int n_in,
                              void* d_out, int out_size, void* d_ws, size_t ws_size,
                              hipStream_t stream)
{
    (void)in_sizes; (void)n_in; (void)out_size; (void)ws_size;
    const float* x  = (const float*)d_in[0];
    const float* Wq = (const float*)d_in[1];
    const float* Wk = (const float*)d_in[2];
    const float* Wv = (const float*)d_in[3];
    const float* fc = (const float*)d_in[4];
    const float* fs = (const float*)d_in[5];
    float* out = (float*)d_out;

    const size_t NW = (size_t)3 * 128 * 1024;
    const size_t NE = (size_t)BT * 128;
    unsigned short* wth = (unsigned short*)d_ws;
    unsigned short* wtl = wth + NW;
    unsigned short* qh  = wtl + NW;
    unsigned short* qlo = qh  + NE;
    unsigned short* kh  = qlo + NE;
    unsigned short* klo = kh  + NE;
    unsigned short* vb  = klo + NE;
    unsigned short* vt  = vb  + NE;
    float* opart  = (float*)(vt + NE);                       // 2176*64*128 f32
    float* mlpart = opart + (size_t)4 * NSLOT * 64 * 128;    // 2176*128 f32

    prep_w_kernel<<<dim3(16, 4, 3), 256, 0, stream>>>(Wq, Wk, Wv, wth, wtl);
    qkv_gemm_kernel<<<dim3(BT / 64, 3), 256, 0, stream>>>(
        x, wth, wtl, fc, fs, qh, qlo, kh, klo, vb);
    vtrans_kernel<<<256, 256, 0, stream>>>(vb, vt);
    attn_chunk_kernel<<<4096, 128, 0, stream>>>(qh, qlo, kh, klo, vt, opart, mlpart);
    combine_kernel<<<256, 256, 0, stream>>>(opart, mlpart, out);
}